// Round 6
// baseline (194.405 us; speedup 1.0000x reference)
//
#include <hip/hip_runtime.h>
#include <math.h>

#define B_  2
#define D_  1536
#define L_  2048
#define N_  16
#define LC  128               // chunk length along L (16 segs x 8 elems)
#define NCHUNK (L_ / LC)      // 16
#define NCH (B_ * D_)         // 3072 channels
#define LOG2E 1.4426950408889634f
#define LN2   0.6931471805599453f

typedef float f4 __attribute__((ext_vector_type(4)));
typedef float f8 __attribute__((ext_vector_type(8)));

__device__ __forceinline__ float exp2f_(float v) { return __builtin_amdgcn_exp2f(v); }
__device__ __forceinline__ float log2f_(float v) { return __builtin_amdgcn_logf(v); }
__device__ __forceinline__ float rcpf_(float v)  { return __builtin_amdgcn_rcpf(v); }

__device__ __forceinline__ f8 splat8(float v) { f8 r = {v,v,v,v,v,v,v,v}; return r; }
__device__ __forceinline__ f8 exp2v8(f8 a) {
    f8 r;
    r[0]=exp2f_(a[0]); r[1]=exp2f_(a[1]); r[2]=exp2f_(a[2]); r[3]=exp2f_(a[3]);
    r[4]=exp2f_(a[4]); r[5]=exp2f_(a[5]); r[6]=exp2f_(a[6]); r[7]=exp2f_(a[7]);
    return r;
}
__device__ __forceinline__ f8 softplus8(f8 v) {
    f8 r;
#pragma unroll
    for (int j = 0; j < 8; ++j) {
        float t = exp2f_(v[j] * LOG2E);            // e^v
        float u = LN2 * log2f_(1.0f + t);          // ln(1+e^v)
        r[j] = (v[j] > 20.0f) ? v[j] : u;
    }
    return r;
}

// One wave (=one block) per channel. lane=(g,s): g=lane>>4 owns states
// [4g,4g+4), s=lane&15 owns 8 consecutive L-elems of each 128-chunk.
// f8 row loads consumed directly (no transpose movs). 4-step width-16 shfl
// scan over 4 (P,S) pairs. e saved in f8s, reused in pass 2. All state SSA.
__global__ __launch_bounds__(64, 3)
void ssm_scan_kernel(const float* __restrict__ x,
                     const float* __restrict__ delta,
                     const float* __restrict__ A,
                     const float* __restrict__ Bm,
                     const float* __restrict__ Cm,
                     const float* __restrict__ Dv,
                     const float* __restrict__ z,
                     const float* __restrict__ dbias,
                     float* __restrict__ out)
{
    const int lane = threadIdx.x;      // 0..63
    const int s    = lane & 15;        // L-segment within chunk
    const int g    = lane >> 4;        // state group: states [4g, 4g+4)
    const int ch   = blockIdx.x;
    const int b    = ch / D_;
    const int d    = ch - b * D_;

    const float bias = dbias[d];
    const float Dd   = Dv[d];

    const float* Ab = A + d * N_ + 4 * g;
    f4 A2 = { Ab[0]*LOG2E, Ab[1]*LOG2E, Ab[2]*LOG2E, Ab[3]*LOG2E };

    const float* Bp = Bm + (size_t)b * (N_ * L_) + (size_t)(4 * g) * L_;
    const float* Cp = Cm + (size_t)b * (N_ * L_) + (size_t)(4 * g) * L_;
    const size_t chbase = (size_t)ch * L_;

    f4 carry = {0.0f, 0.0f, 0.0f, 0.0f};

    for (int c = 0; c < NCHUNK; ++c) {
        const int off = c * LC + s * 8;

        // ---- loads (f8 = 2x dwordx4 each, all 32B-aligned) ----
        f8 dv = *(const f8*)(delta + chbase + off);
        f8 xv = *(const f8*)(x     + chbase + off);
        f8 zv = *(const f8*)(z     + chbase + off);
        f8 Bv0 = *(const f8*)(Bp + 0 * L_ + off);
        f8 Bv1 = *(const f8*)(Bp + 1 * L_ + off);
        f8 Bv2 = *(const f8*)(Bp + 2 * L_ + off);
        f8 Bv3 = *(const f8*)(Bp + 3 * L_ + off);
        f8 Cv0 = *(const f8*)(Cp + 0 * L_ + off);
        f8 Cv1 = *(const f8*)(Cp + 1 * L_ + off);
        f8 Cv2 = *(const f8*)(Cp + 2 * L_ + off);
        f8 Cv3 = *(const f8*)(Cp + 3 * L_ + off);

        // ---- dt / u / dtsum ----
        f8 dt = softplus8(dv + splat8(bias));
        f8 u  = dt * xv;
        float dtsum = ((dt[0]+dt[1]) + (dt[2]+dt[3])) + ((dt[4]+dt[5]) + (dt[6]+dt[7]));

        // ---- per-cell deltaA (saved, reused in pass 2) ----
        f8 e0 = exp2v8(dt * splat8(A2[0]));
        f8 e1 = exp2v8(dt * splat8(A2[1]));
        f8 e2 = exp2v8(dt * splat8(A2[2]));
        f8 e3 = exp2v8(dt * splat8(A2[3]));
        f4 P = { exp2f_(dtsum * A2[0]), exp2f_(dtsum * A2[1]),
                 exp2f_(dtsum * A2[2]), exp2f_(dtsum * A2[3]) };

        f8 uB0 = u * Bv0;
        f8 uB1 = u * Bv1;
        f8 uB2 = u * Bv2;
        f8 uB3 = u * Bv3;

        // ---- pass 1: per-lane serial scan of 8 elems (h_in = 0) ----
        f4 S;
#define LOCAL_SCAN(i) { float acc = uB##i[0]; \
        acc = fmaf(e##i[1], acc, uB##i[1]); \
        acc = fmaf(e##i[2], acc, uB##i[2]); \
        acc = fmaf(e##i[3], acc, uB##i[3]); \
        acc = fmaf(e##i[4], acc, uB##i[4]); \
        acc = fmaf(e##i[5], acc, uB##i[5]); \
        acc = fmaf(e##i[6], acc, uB##i[6]); \
        acc = fmaf(e##i[7], acc, uB##i[7]); \
        S[i] = acc; }
        LOCAL_SCAN(0) LOCAL_SCAN(1) LOCAL_SCAN(2) LOCAL_SCAN(3)

        // ---- branchless width-16 inclusive scan of (P,S), 4 steps ----
#pragma unroll
        for (int o = 1; o < 16; o <<= 1) {
#define SCANI(i) { float Pp = __shfl_up(P[i], o, 16); \
                   float Sp = __shfl_up(S[i], o, 16); \
                   Pp = (s >= o) ? Pp : 1.0f; \
                   Sp = (s >= o) ? Sp : 0.0f; \
                   S[i] = fmaf(Sp, P[i], S[i]); \
                   P[i] = P[i] * Pp; }
            SCANI(0) SCANI(1) SCANI(2) SCANI(3)
        }

        // ---- fold chunk carry; h entering this lane's segment ----
        f4 h;
#define CARRYI(i) { float hinc = fmaf(carry[i], P[i], S[i]); \
                    float hup  = __shfl_up(hinc, 1, 16); \
                    h[i] = (s == 0) ? carry[i] : hup; \
                    carry[i] = __shfl(hinc, 15, 16); }
        CARRYI(0) CARRYI(1) CARRYI(2) CARRYI(3)

        // ---- pass 2: recurrence from h_in (reuse e, uB); y_j = sum_i h C ----
        f8 y = splat8(0.0f);
#define PASS2(i) { float hi = h[i]; \
        hi = fmaf(e##i[0], hi, uB##i[0]); y[0] = fmaf(hi, Cv##i[0], y[0]); \
        hi = fmaf(e##i[1], hi, uB##i[1]); y[1] = fmaf(hi, Cv##i[1], y[1]); \
        hi = fmaf(e##i[2], hi, uB##i[2]); y[2] = fmaf(hi, Cv##i[2], y[2]); \
        hi = fmaf(e##i[3], hi, uB##i[3]); y[3] = fmaf(hi, Cv##i[3], y[3]); \
        hi = fmaf(e##i[4], hi, uB##i[4]); y[4] = fmaf(hi, Cv##i[4], y[4]); \
        hi = fmaf(e##i[5], hi, uB##i[5]); y[5] = fmaf(hi, Cv##i[5], y[5]); \
        hi = fmaf(e##i[6], hi, uB##i[6]); y[6] = fmaf(hi, Cv##i[6], y[6]); \
        hi = fmaf(e##i[7], hi, uB##i[7]); y[7] = fmaf(hi, Cv##i[7], y[7]); }
        PASS2(0) PASS2(1) PASS2(2) PASS2(3)

        // ---- combine the 4 state-groups ----
#pragma unroll
        for (int j = 0; j < 8; ++j) {
            y[j] += __shfl_xor(y[j], 16, 64);
            y[j] += __shfl_xor(y[j], 32, 64);
        }

        // ---- epilogue: D-skip + SiLU gate; group 0 stores (512B/wave) ----
        f8 ov;
#pragma unroll
        for (int j = 0; j < 8; ++j) {
            float sig = rcpf_(1.0f + exp2f_(-zv[j] * LOG2E));
            ov[j] = (y[j] + xv[j] * Dd) * (zv[j] * sig);
        }
        if (g == 0) {
            *(f8*)(out + chbase + off) = ov;
        }
    }
}

extern "C" void kernel_launch(void* const* d_in, const int* in_sizes, int n_in,
                              void* d_out, int out_size, void* d_ws, size_t ws_size,
                              hipStream_t stream) {
    const float* x     = (const float*)d_in[0];
    const float* delta = (const float*)d_in[1];
    const float* A     = (const float*)d_in[2];
    const float* Bm    = (const float*)d_in[3];
    const float* Cm    = (const float*)d_in[4];
    const float* Dv    = (const float*)d_in[5];
    const float* z     = (const float*)d_in[6];
    const float* dbias = (const float*)d_in[7];
    float* out = (float*)d_out;

    dim3 grid(NCH);    // 3072 blocks = 1 wave = 1 channel each
    dim3 block(64);
    ssm_scan_kernel<<<grid, block, 0, stream>>>(x, delta, A, Bm, Cm, Dv, z, dbias, out);
}

// Round 8
// 171.510 us; speedup vs baseline: 1.1335x; 1.1335x over previous
//
#include <hip/hip_runtime.h>
#include <math.h>

#define B_  2
#define D_  1536
#define L_  2048
#define N_  16
#define NH  8                 // states per half-wave
#define LC  128               // chunk length along L (32 segs x 4 elems)
#define NCHUNK (L_ / LC)      // 16
#define NCH (B_ * D_)         // 3072 channels
#define LOG2E 1.4426950408889634f
#define LN2   0.6931471805599453f

typedef float f4 __attribute__((ext_vector_type(4)));
typedef float f8 __attribute__((ext_vector_type(8)));

__device__ __forceinline__ float exp2f_(float v) { return __builtin_amdgcn_exp2f(v); }
__device__ __forceinline__ float log2f_(float v) { return __builtin_amdgcn_logf(v); }
__device__ __forceinline__ float rcpf_(float v)  { return __builtin_amdgcn_rcpf(v); }

__device__ __forceinline__ float softplus_f(float v) {
    float t = exp2f_(v * LOG2E);                   // e^v
    float r = LN2 * log2f_(1.0f + t);              // ln(1+e^v)
    return (v > 20.0f) ? v : r;
}
__device__ __forceinline__ f8 splat8(float v) { f8 r = {v,v,v,v,v,v,v,v}; return r; }
__device__ __forceinline__ f8 exp2v8(f8 a) {
    f8 r;
    r[0]=exp2f_(a[0]); r[1]=exp2f_(a[1]); r[2]=exp2f_(a[2]); r[3]=exp2f_(a[3]);
    r[4]=exp2f_(a[4]); r[5]=exp2f_(a[5]); r[6]=exp2f_(a[6]); r[7]=exp2f_(a[7]);
    return r;
}
__device__ __forceinline__ float dot8(f8 a, f8 b) {
    float p0 = fmaf(a[0], b[0], a[1]*b[1]);
    float p1 = fmaf(a[2], b[2], a[3]*b[3]);
    float p2 = fmaf(a[4], b[4], a[5]*b[5]);
    float p3 = fmaf(a[6], b[6], a[7]*b[7]);
    return (p0 + p1) + (p2 + p3);
}

// DPP move with explicit identity for invalid/masked lanes (bound_ctrl=false
// and masked rows both produce `old`).
#define DPP_ROW_SHR(N) (0x110 + (N))
#define DPP_ROW_BCAST15 0x142
#define DPP_WAVE_SHR1   0x138
template<int CTRL, int RMASK>
__device__ __forceinline__ float updpp(float old, float v) {
    return __int_as_float(__builtin_amdgcn_update_dpp(
        __float_as_int(old), __float_as_int(v), CTRL, RMASK, 0xF, false));
}

// One wave (= one 64-thread block) per channel. lane=(g,s): g=lane>>5 owns 8
// of 16 states, s=lane&31 owns a 4-elem L-segment of each 128-chunk.
// No LDS/barriers; B/C per-lane float4 from global (L2-hot, coalesced per
// half-wave). All state in ext-vector SSA (scratch-free, WRITE=output only).
// Width-32 scan entirely on the VALU pipe via DPP: row_shr 1/2/4/8 scans each
// 16-lane row; row_bcast15 with row_mask=0xA folds row0->row1 and row2->row3
// ONLY (mask keeps rows 0/2 at the neutral element — row_bcast15 would
// otherwise leak lane31 (g=0 total) into row2, which is g=1's scan start;
// that leak was round 7's correctness bug).
__global__ __launch_bounds__(64, 3)
void ssm_scan_kernel(const float* __restrict__ x,
                     const float* __restrict__ delta,
                     const float* __restrict__ A,
                     const float* __restrict__ Bm,
                     const float* __restrict__ Cm,
                     const float* __restrict__ Dv,
                     const float* __restrict__ z,
                     const float* __restrict__ dbias,
                     float* __restrict__ out)
{
    const int lane = threadIdx.x;      // 0..63
    const int s    = lane & 31;
    const int g    = lane >> 5;
    const int ch   = blockIdx.x;       // one channel per wave
    const int b    = ch / D_;
    const int d    = ch - b * D_;

    const float bias = dbias[d];
    const float Dd   = Dv[d];

    const float* Ab = A + d * N_ + NH * g;
    f8 A2v;
    A2v[0]=Ab[0]*LOG2E; A2v[1]=Ab[1]*LOG2E; A2v[2]=Ab[2]*LOG2E; A2v[3]=Ab[3]*LOG2E;
    A2v[4]=Ab[4]*LOG2E; A2v[5]=Ab[5]*LOG2E; A2v[6]=Ab[6]*LOG2E; A2v[7]=Ab[7]*LOG2E;

    const float* Bp = Bm + (size_t)b * (N_ * L_) + (size_t)(NH * g) * L_;
    const float* Cp = Cm + (size_t)b * (N_ * L_) + (size_t)(NH * g) * L_;
    const size_t chbase = (size_t)ch * L_;

    f8 carry = splat8(0.0f);

    for (int c = 0; c < NCHUNK; ++c) {
        const int off = c * LC + s * 4;

        // ---- loads: delta first (dt chain starts), then x/z, then B/C ----
        f4 dv = *(const f4*)(delta + chbase + off);
        f4 xv = *(const f4*)(x     + chbase + off);
        f4 zv = *(const f4*)(z     + chbase + off);
#define LD_BC(i) f4 Bv##i = *(const f4*)(Bp + i * L_ + off); \
                 f4 Cv##i = *(const f4*)(Cp + i * L_ + off);
        LD_BC(0) LD_BC(1) LD_BC(2) LD_BC(3) LD_BC(4) LD_BC(5) LD_BC(6) LD_BC(7)

        // ---- dt / u / dtsum ----
        float dt0 = softplus_f(dv.x + bias);
        float dt1 = softplus_f(dv.y + bias);
        float dt2 = softplus_f(dv.z + bias);
        float dt3 = softplus_f(dv.w + bias);
        float u0 = dt0 * xv.x, u1 = dt1 * xv.y, u2 = dt2 * xv.z, u3 = dt3 * xv.w;
        float dtsum = (dt0 + dt1) + (dt2 + dt3);

        // ---- per-element deltaA vectors (kept for pass 2) ----
        f8 e0 = exp2v8(splat8(dt0) * A2v);
        f8 e1 = exp2v8(splat8(dt1) * A2v);
        f8 e2 = exp2v8(splat8(dt2) * A2v);
        f8 e3 = exp2v8(splat8(dt3) * A2v);
        f8 P  = exp2v8(splat8(dtsum) * A2v);

        // ---- transpose B/C fragments to per-j state-vectors ----
        f8 tB0 = {Bv0.x,Bv1.x,Bv2.x,Bv3.x,Bv4.x,Bv5.x,Bv6.x,Bv7.x};
        f8 tB1 = {Bv0.y,Bv1.y,Bv2.y,Bv3.y,Bv4.y,Bv5.y,Bv6.y,Bv7.y};
        f8 tB2 = {Bv0.z,Bv1.z,Bv2.z,Bv3.z,Bv4.z,Bv5.z,Bv6.z,Bv7.z};
        f8 tB3 = {Bv0.w,Bv1.w,Bv2.w,Bv3.w,Bv4.w,Bv5.w,Bv6.w,Bv7.w};
        f8 uB0 = splat8(u0) * tB0;
        f8 uB1 = splat8(u1) * tB1;
        f8 uB2 = splat8(u2) * tB2;
        f8 uB3 = splat8(u3) * tB3;
        f8 SC0 = {Cv0.x,Cv1.x,Cv2.x,Cv3.x,Cv4.x,Cv5.x,Cv6.x,Cv7.x};
        f8 SC1 = {Cv0.y,Cv1.y,Cv2.y,Cv3.y,Cv4.y,Cv5.y,Cv6.y,Cv7.y};
        f8 SC2 = {Cv0.z,Cv1.z,Cv2.z,Cv3.z,Cv4.z,Cv5.z,Cv6.z,Cv7.z};
        f8 SC3 = {Cv0.w,Cv1.w,Cv2.w,Cv3.w,Cv4.w,Cv5.w,Cv6.w,Cv7.w};

        // ---- pass 1: local 4-elem scan (start h=0) ----
        f8 S = uB0;
        S = e1 * S + uB1;
        S = e2 * S + uB2;
        S = e3 * S + uB3;

        // ---- width-32 inclusive scan of (P,S), all DPP/VALU ----
#define SCAN_STEP(CTRL, RMASK) \
        { \
            _Pragma("unroll") \
            for (int i = 0; i < NH; ++i) { \
                float Pp = updpp<CTRL, RMASK>(1.0f, P[i]); \
                float Sp = updpp<CTRL, RMASK>(0.0f, S[i]); \
                S[i] = fmaf(Sp, P[i], S[i]);   /* uses pre-update P */ \
                P[i] = P[i] * Pp; \
            } \
        }
        SCAN_STEP(DPP_ROW_SHR(1), 0xF)
        SCAN_STEP(DPP_ROW_SHR(2), 0xF)
        SCAN_STEP(DPP_ROW_SHR(4), 0xF)
        SCAN_STEP(DPP_ROW_SHR(8), 0xF)
        SCAN_STEP(DPP_ROW_BCAST15, 0xA)  // rows 1,3 only; rows 0,2 keep neutral

        // ---- fold chunk carry; h entering this lane's segment ----
        f8 h;
#pragma unroll
        for (int i = 0; i < NH; ++i) {
            float hinc = fmaf(carry[i], P[i], S[i]);        // true inclusive state
            float hup  = updpp<DPP_WAVE_SHR1, 0xF>(0.0f, hinc); // lane n <- n-1
            h[i] = (s == 0) ? carry[i] : hup;               // fixes lanes 0 and 32
            carry[i] = __shfl(hinc, 31, 32);                // broadcast within half
        }

        // ---- pass 2: recurrence (reusing e_j, uB_j); y_j = <h, C_j> ----
        h = e0 * h + uB0;  float y0 = dot8(h, SC0);
        h = e1 * h + uB1;  float y1 = dot8(h, SC1);
        h = e2 * h + uB2;  float y2 = dot8(h, SC2);
        h = e3 * h + uB3;  float y3 = dot8(h, SC3);

        // ---- combine the two state-halves; epilogue; half-wave store ----
        y0 += __shfl_xor(y0, 32, 64);
        y1 += __shfl_xor(y1, 32, 64);
        y2 += __shfl_xor(y2, 32, 64);
        y3 += __shfl_xor(y3, 32, 64);
        if (g == 0) {
            float s0 = rcpf_(1.0f + exp2f_(-zv.x * LOG2E));
            float s1 = rcpf_(1.0f + exp2f_(-zv.y * LOG2E));
            float s2 = rcpf_(1.0f + exp2f_(-zv.z * LOG2E));
            float s3 = rcpf_(1.0f + exp2f_(-zv.w * LOG2E));
            f4 ov = { (y0 + xv.x * Dd) * (zv.x * s0),
                      (y1 + xv.y * Dd) * (zv.y * s1),
                      (y2 + xv.z * Dd) * (zv.z * s2),
                      (y3 + xv.w * Dd) * (zv.w * s3) };
            *(f4*)(out + chbase + off) = ov;
        }
    }
}

extern "C" void kernel_launch(void* const* d_in, const int* in_sizes, int n_in,
                              void* d_out, int out_size, void* d_ws, size_t ws_size,
                              hipStream_t stream) {
    const float* x     = (const float*)d_in[0];
    const float* delta = (const float*)d_in[1];
    const float* A     = (const float*)d_in[2];
    const float* Bm    = (const float*)d_in[3];
    const float* Cm    = (const float*)d_in[4];
    const float* Dv    = (const float*)d_in[5];
    const float* z     = (const float*)d_in[6];
    const float* dbias = (const float*)d_in[7];
    float* out = (float*)d_out;

    dim3 grid(NCH);    // 3072 blocks = 1 wave = 1 channel each
    dim3 block(64);
    ssm_scan_kernel<<<grid, block, 0, stream>>>(x, delta, A, Bm, Cm, Dv, z, dbias, out);
}